// Round 1
// baseline (75.663 us; speedup 1.0000x reference)
//
#include <hip/hip_runtime.h>
#include <stdint.h>

// quantizer_channel: out[e] = center[ argmin_k|x[e]-c[k]| ^ noise_mask(e) ]
// noise bits reproduce jax.random.bernoulli(key(42), 0.01, [B,C,H,W,4]) under
// the partitionable threefry2x32 implementation (default in modern JAX):
//   draw i (uint32) = w0^w1 of threefry2x32(key=(0,42), block=(0, i))
//   bit = ( (draw >> 9) <= 83886 )        // == uniform(draw) < 0.01f exactly

#define KS1 42u
#define KS2 0x1BD11BF0u   // 0 ^ 42 ^ 0x1BD11BDA

#define TF_ROUND4(r)                                            \
  { _Pragma("unroll") for (int j = 0; j < 4; ++j) {             \
      y0[j] += y1[j];                                           \
      y1[j] = (y1[j] << (r)) | (y1[j] >> (32 - (r)));           \
      y1[j] ^= y0[j];                                           \
  } }

#define TF_INJ4(a, b)                                           \
  { _Pragma("unroll") for (int j = 0; j < 4; ++j) {             \
      y0[j] += (a); y1[j] += (b);                               \
  } }

__global__ __launch_bounds__(256) void quantizer_channel_kernel(
    const float* __restrict__ x, const float* __restrict__ center,
    float* __restrict__ out, int n4)
{
  int t = blockIdx.x * blockDim.x + threadIdx.x;
  if (t >= n4) return;

  // centers: uniform address -> scalar loads; one 64B line holds all 16
  float c[16];
#pragma unroll
  for (int k = 0; k < 16; ++k) c[k] = center[k];

  const float4 xv = reinterpret_cast<const float4*>(x)[t];
  float xe[4] = {xv.x, xv.y, xv.z, xv.w};
  float oe[4];

  const uint32_t ctr_base = (uint32_t)t * 16u;  // 4 elems * 4 bits

#pragma unroll
  for (int e = 0; e < 4; ++e) {
    // ---- argmin over 16 centers (first-min tie-break, matches jnp.argmin)
    const float v = xe[e];
    float bd = fabsf(v - c[0]);
    int best = 0;
#pragma unroll
    for (int k = 1; k < 16; ++k) {
      const float d = fabsf(v - c[k]);
      best = (d < bd) ? k : best;
      bd = fminf(d, bd);
    }

    // ---- 4 interleaved threefry2x32 chains, counters (0, ctr_base+4e+j)
    uint32_t y0[4], y1[4];
#pragma unroll
    for (int j = 0; j < 4; ++j) {
      y0[j] = 0u;                                  // hi word + ks0(=0)
      y1[j] = (ctr_base + 4u * (uint32_t)e + (uint32_t)j) + KS1;
    }
    TF_ROUND4(13) TF_ROUND4(15) TF_ROUND4(26) TF_ROUND4(6)
    TF_INJ4(KS1, KS2 + 1u)
    TF_ROUND4(17) TF_ROUND4(29) TF_ROUND4(16) TF_ROUND4(24)
    TF_INJ4(KS2, 0u + 2u)
    TF_ROUND4(13) TF_ROUND4(15) TF_ROUND4(26) TF_ROUND4(6)
    TF_INJ4(0u, KS1 + 3u)
    TF_ROUND4(17) TF_ROUND4(29) TF_ROUND4(16) TF_ROUND4(24)
    TF_INJ4(KS1, KS2 + 4u)
    TF_ROUND4(13) TF_ROUND4(15) TF_ROUND4(26) TF_ROUND4(6)
    TF_INJ4(KS2, 0u + 5u)

    uint32_t flip = 0u;
#pragma unroll
    for (int j = 0; j < 4; ++j) {
      const uint32_t bits = y0[j] ^ y1[j];
      // uniform(bits) < 0.01f  <=>  mantissa (bits>>9) <= 83886
      const uint32_t hit = ((bits >> 9) <= 83886u) ? 1u : 0u;
      flip |= hit << (3 - j);                      // MSB-first bit order
    }

    oe[e] = center[(uint32_t)best ^ flip];         // 16 floats = 1 cache line
  }

  float4 o4;
  o4.x = oe[0]; o4.y = oe[1]; o4.z = oe[2]; o4.w = oe[3];
  reinterpret_cast<float4*>(out)[t] = o4;
}

extern "C" void kernel_launch(void* const* d_in, const int* in_sizes, int n_in,
                              void* d_out, int out_size, void* d_ws, size_t ws_size,
                              hipStream_t stream)
{
  const float* x      = (const float*)d_in[0];
  const float* center = (const float*)d_in[1];
  float* out          = (float*)d_out;

  const int N  = in_sizes[0];          // 32*256*32*32 = 8388608, divisible by 4
  const int n4 = N / 4;
  const int block = 256;
  const int grid  = (n4 + block - 1) / block;

  hipLaunchKernelGGL(quantizer_channel_kernel, dim3(grid), dim3(block), 0, stream,
                     x, center, out, n4);
}

// Round 2
// 75.628 us; speedup vs baseline: 1.0005x; 1.0005x over previous
//
#include <hip/hip_runtime.h>
#include <stdint.h>

// quantizer_channel: out[e] = center[ argmin_k|x[e]-c[k]| ^ noise_mask(e) ]
// noise bits reproduce jax.random.bernoulli(key(42), 0.01, [B,C,H,W,4]) under
// partitionable threefry2x32 (modern JAX default):
//   draw i (uint32) = w0^w1 of threefry2x32(key=(0,42), block=(0, i))
//   bit = draw < 83887u<<9      // == ((draw>>9) <= 83886) == uniform(draw) < 0.01f

#define KS1 42u
#define KS2 0x1BD11BF0u   // 0x1BD11BDA ^ 0 ^ 42
#define BERN_LT 42950144u // 83887 << 9

// single-instruction rotl: v_alignbit_b32 dst, x, x, (32-r)
__device__ __forceinline__ uint32_t rotl(uint32_t x, int r) {
  return __builtin_amdgcn_alignbit(x, x, (32 - r) & 31);
}

#define TF_ROUND4(r)                                            \
  { _Pragma("unroll") for (int j = 0; j < 4; ++j) {             \
      y0[j] += y1[j];                                           \
      y1[j] = rotl(y1[j], (r)) ^ y0[j];                         \
  } }

#define TF_INJ4(a, b)                                           \
  { _Pragma("unroll") for (int j = 0; j < 4; ++j) {             \
      y0[j] += (a); y1[j] += (b);                               \
  } }

__global__ __launch_bounds__(256) void quantizer_channel_kernel(
    const float* __restrict__ x, const float* __restrict__ center,
    float* __restrict__ out, int n4)
{
  int t = blockIdx.x * blockDim.x + threadIdx.x;
  if (t >= n4) return;

  // centers: uniform address -> scalar loads; one 64B line holds all 16
  float c[16];
#pragma unroll
  for (int k = 0; k < 16; ++k) c[k] = center[k];

  const float4 xv = reinterpret_cast<const float4*>(x)[t];
  float xe[4] = {xv.x, xv.y, xv.z, xv.w};
  float oe[4];

  const uint32_t ctr_base = (uint32_t)t * 16u;  // 4 elems * 4 bits

#pragma unroll
  for (int e = 0; e < 4; ++e) {
    // ---- argmin over 16 centers (first-min tie-break, matches jnp.argmin)
    const float v = xe[e];
    float bd = fabsf(v - c[0]);
    int best = 0;
#pragma unroll
    for (int k = 1; k < 16; ++k) {
      const float d = fabsf(v - c[k]);
      best = (d < bd) ? k : best;
      bd = fminf(d, bd);
    }

    // ---- 4 interleaved threefry2x32 chains, counters (0, ctr_base+4e+j)
    uint32_t y0[4], y1[4];
#pragma unroll
    for (int j = 0; j < 4; ++j) {
      y0[j] = 0u;                                  // ctr_hi(0) + ks0(0)
      y1[j] = (ctr_base + 4u * (uint32_t)e + (uint32_t)j) + KS1;
    }
    TF_ROUND4(13) TF_ROUND4(15) TF_ROUND4(26) TF_ROUND4(6)
    TF_INJ4(KS1, KS2 + 1u)
    TF_ROUND4(17) TF_ROUND4(29) TF_ROUND4(16) TF_ROUND4(24)
    TF_INJ4(KS2, 0u + 2u)
    TF_ROUND4(13) TF_ROUND4(15) TF_ROUND4(26) TF_ROUND4(6)
    TF_INJ4(0u, KS1 + 3u)
    TF_ROUND4(17) TF_ROUND4(29) TF_ROUND4(16) TF_ROUND4(24)
    TF_INJ4(KS1, KS2 + 4u)
    TF_ROUND4(13) TF_ROUND4(15) TF_ROUND4(26) TF_ROUND4(6)
    TF_INJ4(KS2, 0u + 5u)

    uint32_t flip = 0u;
#pragma unroll
    for (int j = 0; j < 4; ++j) {
      const uint32_t bits = y0[j] ^ y1[j];
      const uint32_t hit = (bits < BERN_LT) ? 1u : 0u;  // single v_cmp
      flip |= hit << (3 - j);                           // MSB-first bit order
    }

    oe[e] = center[(uint32_t)best ^ flip];         // 16 floats = 1 cache line
  }

  float4 o4;
  o4.x = oe[0]; o4.y = oe[1]; o4.z = oe[2]; o4.w = oe[3];
  reinterpret_cast<float4*>(out)[t] = o4;
}

extern "C" void kernel_launch(void* const* d_in, const int* in_sizes, int n_in,
                              void* d_out, int out_size, void* d_ws, size_t ws_size,
                              hipStream_t stream)
{
  const float* x      = (const float*)d_in[0];
  const float* center = (const float*)d_in[1];
  float* out          = (float*)d_out;

  const int N  = in_sizes[0];          // 32*256*32*32 = 8388608, divisible by 4
  const int n4 = N / 4;
  const int block = 256;
  const int grid  = (n4 + block - 1) / block;

  hipLaunchKernelGGL(quantizer_channel_kernel, dim3(grid), dim3(block), 0, stream,
                     x, center, out, n4);
}

// Round 3
// 74.428 us; speedup vs baseline: 1.0166x; 1.0161x over previous
//
#include <hip/hip_runtime.h>
#include <stdint.h>

// quantizer_channel: out[e] = center[ nearest_idx(x[e]) ^ noise_mask(e) ]
//
// nearest_idx == jnp.argmin(|x - center|) reproduced EXACTLY via a sorted
// binary search whose 15 thresholds are bit-bisected in a setup kernel
// against the reference predicate (f32 rounded distances, first-original-
// index tie-break).
//
// noise bits reproduce jax.random.bernoulli(key(42), 0.01, [B,C,H,W,4])
// under partitionable threefry2x32 (modern JAX default):
//   draw i (uint32) = w0^w1 of threefry2x32(key=(0,42), block=(0, i))
//   bit = draw < (83887u << 9)   // == uniform(draw) < 0.01f exactly

#define KS1 42u
#define KS2 0x1BD11BF0u   // 0x1BD11BDA ^ 0 ^ 42
#define BERN_LT 42950144u // 83887 << 9

// ---------- ordered-float <-> key (monotone total order over floats) ------
__device__ __forceinline__ uint32_t fkey(float f) {
  uint32_t u = __float_as_uint(f);
  return (u & 0x80000000u) ? ~u : (u | 0x80000000u);
}
__device__ __forceinline__ float finv(uint32_t k) {
  uint32_t u = (k & 0x80000000u) ? (k & 0x7fffffffu) : ~k;
  return __uint_as_float(u);
}

// ---------- setup: sort centers, bisect exact cell thresholds -------------
// ws layout (32-bit words): [0..14] = T0..T14 (float thresholds, sorted order)
//                           [15]    = pad
//                           [16]    = lut0 (orig idx of sorted 0..7, 4b each)
//                           [17]    = lut1 (orig idx of sorted 8..15)
__global__ void quantizer_setup_kernel(const float* __restrict__ center,
                                       float* __restrict__ ws) {
  const int t = threadIdx.x;
  __shared__ float sval[16];
  __shared__ int   sidx[16];
  if (t < 16) {
    const float ct = center[t];
    int rank = 0;
    for (int j = 0; j < 16; ++j) {
      const float cj = center[j];
      rank += (cj < ct || (cj == ct && j < t)) ? 1 : 0;
    }
    sval[rank] = ct;
    sidx[rank] = t;
  }
  __syncthreads();
  if (t < 15) {
    const float sL = sval[t], sR = sval[t + 1];
    const bool tieLeft = sidx[t] < sidx[t + 1];   // tie -> smaller orig idx
    uint32_t lo = fkey(sL), hi = fkey(sR);        // P(lo)=true, P(hi)=false
    while (hi - lo > 1u) {
      const uint32_t mid = lo + ((hi - lo) >> 1);
      const float xm = finv(mid);
      const float dL = fabsf(xm - sL);            // exactly reference's fl ops
      const float dR = fabsf(xm - sR);
      const bool left = (dL < dR) || (dL == dR && tieLeft);
      if (left) lo = mid; else hi = mid;
    }
    ws[t] = finv(lo);                             // largest float where left wins
  }
  if (t == 15) {
    uint32_t l0 = 0, l1 = 0;
    for (int p = 0; p < 8; ++p) l0 |= ((uint32_t)sidx[p])     << (4 * p);
    for (int p = 0; p < 8; ++p) l1 |= ((uint32_t)sidx[p + 8]) << (4 * p);
    uint32_t* wu = (uint32_t*)ws;
    wu[15] = 0u;
    wu[16] = l0;
    wu[17] = l1;
  }
}

// ---------- threefry helpers ----------------------------------------------
__device__ __forceinline__ uint32_t rotl(uint32_t x, int r) {
  return __builtin_amdgcn_alignbit(x, x, (32 - r) & 31);
}
#define TF_ROUND4(r)                                            \
  { _Pragma("unroll") for (int j = 0; j < 4; ++j) {             \
      y0[j] += y1[j];                                           \
      y1[j] = rotl(y1[j], (r)) ^ y0[j];                         \
  } }
#define TF_INJ4(a, b)                                           \
  { _Pragma("unroll") for (int j = 0; j < 4; ++j) {             \
      y0[j] += (a); y1[j] += (b);                               \
  } }

// ---------- main -----------------------------------------------------------
__global__ __launch_bounds__(256) void quantizer_channel_kernel(
    const float* __restrict__ x, const float* __restrict__ center,
    const float* __restrict__ ws, float* __restrict__ out, int n4)
{
  const int t = blockIdx.x * blockDim.x + threadIdx.x;
  if (t >= n4) return;

  // thresholds + luts -> per-thread VGPRs (L1/L2 broadcast-cached)
  const float4* wsf = (const float4*)ws;
  const float4 ta = wsf[0], tb = wsf[1], tc = wsf[2], td = wsf[3];
  const float T0 = ta.x, T1 = ta.y, T2  = ta.z, T3  = ta.w;
  const float T4 = tb.x, T5 = tb.y, T6  = tb.z, T7  = tb.w;
  const float T8 = tc.x, T9 = tc.y, T10 = tc.z, T11 = tc.w;
  const float T12 = td.x, T13 = td.y, T14 = td.z;
  const uint32_t lut0 = ((const uint32_t*)ws)[16];
  const uint32_t lut1 = ((const uint32_t*)ws)[17];

  const float4 xv = reinterpret_cast<const float4*>(x)[t];
  float xe[4] = {xv.x, xv.y, xv.z, xv.w};
  float oe[4];

  const uint32_t ctr_base = (uint32_t)t * 16u;  // 4 elems * 4 bits

#pragma unroll
  for (int e = 0; e < 4; ++e) {
    const float v = xe[e];

    // ---- exact nearest-center via 4-level binary search (cells 0..15)
    const bool b3 = v > T7;
    const float s2 = b3 ? T11 : T3;
    const bool b2 = v > s2;
    const float s1 = b3 ? (b2 ? T13 : T9) : (b2 ? T5 : T1);
    const bool b1 = v > s1;
    const float u0 = b1 ? T2  : T0;
    const float u1 = b1 ? T6  : T4;
    const float u2 = b1 ? T10 : T8;
    const float u3 = b1 ? T14 : T12;
    const float s0 = b3 ? (b2 ? u3 : u2) : (b2 ? u1 : u0);
    const bool b0 = v > s0;
    const uint32_t shamt = (b2 ? 16u : 0u) | (b1 ? 8u : 0u) | (b0 ? 4u : 0u);
    const uint32_t word = b3 ? lut1 : lut0;
    const uint32_t best = (word >> shamt) & 15u;   // original center index

    // ---- 4 interleaved threefry2x32 chains, counters (0, ctr_base+4e+j)
    uint32_t y0[4], y1[4];
#pragma unroll
    for (int j = 0; j < 4; ++j) {
      y0[j] = 0u;                                  // ctr_hi(0) + ks0(0)
      y1[j] = (ctr_base + 4u * (uint32_t)e + (uint32_t)j) + KS1;
    }
    TF_ROUND4(13) TF_ROUND4(15) TF_ROUND4(26) TF_ROUND4(6)
    TF_INJ4(KS1, KS2 + 1u)
    TF_ROUND4(17) TF_ROUND4(29) TF_ROUND4(16) TF_ROUND4(24)
    TF_INJ4(KS2, 0u + 2u)
    TF_ROUND4(13) TF_ROUND4(15) TF_ROUND4(26) TF_ROUND4(6)
    TF_INJ4(0u, KS1 + 3u)
    TF_ROUND4(17) TF_ROUND4(29) TF_ROUND4(16) TF_ROUND4(24)
    TF_INJ4(KS1, KS2 + 4u)
    TF_ROUND4(13) TF_ROUND4(15) TF_ROUND4(26) TF_ROUND4(6)
    TF_INJ4(KS2, 0u + 5u)

    uint32_t flip = 0u;
#pragma unroll
    for (int j = 0; j < 4; ++j) {
      const uint32_t bits = y0[j] ^ y1[j];
      const uint32_t hit = (bits < BERN_LT) ? 1u : 0u;  // single v_cmp
      flip |= hit << (3 - j);                           // MSB-first bit order
    }

    oe[e] = center[best ^ flip];                   // 16 floats = 1 cache line
  }

  float4 o4;
  o4.x = oe[0]; o4.y = oe[1]; o4.z = oe[2]; o4.w = oe[3];
  reinterpret_cast<float4*>(out)[t] = o4;
}

extern "C" void kernel_launch(void* const* d_in, const int* in_sizes, int n_in,
                              void* d_out, int out_size, void* d_ws, size_t ws_size,
                              hipStream_t stream)
{
  const float* x      = (const float*)d_in[0];
  const float* center = (const float*)d_in[1];
  float* out          = (float*)d_out;
  float* ws           = (float*)d_ws;

  hipLaunchKernelGGL(quantizer_setup_kernel, dim3(1), dim3(64), 0, stream,
                     center, ws);

  const int N  = in_sizes[0];          // 32*256*32*32 = 8388608, divisible by 4
  const int n4 = N / 4;
  const int block = 256;
  const int grid  = (n4 + block - 1) / block;

  hipLaunchKernelGGL(quantizer_channel_kernel, dim3(grid), dim3(block), 0, stream,
                     x, center, ws, out, n4);
}

// Round 4
// 74.325 us; speedup vs baseline: 1.0180x; 1.0014x over previous
//
#include <hip/hip_runtime.h>
#include <stdint.h>

// quantizer_channel: out[e] = center[ nearest_idx(x[e]) ^ noise_mask(e) ]
//
// nearest_idx == jnp.argmin(|x - center|) reproduced EXACTLY via a sorted
// binary search whose 15 thresholds are bit-bisected in a setup kernel
// against the reference predicate (f32 rounded distances, first-original-
// index tie-break).
//
// noise bits reproduce jax.random.bernoulli(key(42), 0.01, [B,C,H,W,4])
// under partitionable threefry2x32 (modern JAX default):
//   draw i (uint32) = w0^w1 of threefry2x32(key=(0,42), block=(0, i))
//   bit = draw < (83887u << 9)   // == uniform(draw) < 0.01f exactly

#define KS1 42u
#define KS2 0x1BD11BF0u   // 0x1BD11BDA ^ 0 ^ 42
#define BERN_LT 42950144u // 83887 << 9

// ---------- ordered-float <-> key (monotone total order over floats) ------
__device__ __forceinline__ uint32_t fkey(float f) {
  uint32_t u = __float_as_uint(f);
  return (u & 0x80000000u) ? ~u : (u | 0x80000000u);
}
__device__ __forceinline__ float finv(uint32_t k) {
  uint32_t u = (k & 0x80000000u) ? (k & 0x7fffffffu) : ~k;
  return __uint_as_float(u);
}

// ---------- setup: sort centers, bisect exact cell thresholds -------------
// ws layout (32-bit words): [0..14] = T0..T14 (float thresholds, sorted order)
//                           [15]    = pad
//                           [16]    = lut0 (orig idx of sorted 0..7, 4b each)
//                           [17]    = lut1 (orig idx of sorted 8..15)
__global__ void quantizer_setup_kernel(const float* __restrict__ center,
                                       float* __restrict__ ws) {
  const int t = threadIdx.x;
  __shared__ float sval[16];
  __shared__ int   sidx[16];
  if (t < 16) {
    const float ct = center[t];
    int rank = 0;
    for (int j = 0; j < 16; ++j) {
      const float cj = center[j];
      rank += (cj < ct || (cj == ct && j < t)) ? 1 : 0;
    }
    sval[rank] = ct;
    sidx[rank] = t;
  }
  __syncthreads();
  if (t < 15) {
    const float sL = sval[t], sR = sval[t + 1];
    const bool tieLeft = sidx[t] < sidx[t + 1];   // tie -> smaller orig idx
    uint32_t lo = fkey(sL), hi = fkey(sR);        // P(lo)=true, P(hi)=false
    while (hi - lo > 1u) {
      const uint32_t mid = lo + ((hi - lo) >> 1);
      const float xm = finv(mid);
      const float dL = fabsf(xm - sL);            // exactly reference's fl ops
      const float dR = fabsf(xm - sR);
      const bool left = (dL < dR) || (dL == dR && tieLeft);
      if (left) lo = mid; else hi = mid;
    }
    ws[t] = finv(lo);                             // largest float where left wins
  }
  if (t == 15) {
    uint32_t l0 = 0, l1 = 0;
    for (int p = 0; p < 8; ++p) l0 |= ((uint32_t)sidx[p])     << (4 * p);
    for (int p = 0; p < 8; ++p) l1 |= ((uint32_t)sidx[p + 8]) << (4 * p);
    uint32_t* wu = (uint32_t*)ws;
    wu[15] = 0u;
    wu[16] = l0;
    wu[17] = l1;
  }
}

// ---------- threefry helpers ----------------------------------------------
__device__ __forceinline__ uint32_t rotl(uint32_t x, int r) {
  return __builtin_amdgcn_alignbit(x, x, (32 - r) & 31);
}
// advance all 16 chains one round: 48 instrs, 16-way ILP
#define TF_ROUND_ALL(r)                                         \
  { _Pragma("unroll") for (int q = 0; q < 16; ++q) {            \
      y0[q] += y1[q];                                           \
      y1[q] = rotl(y1[q], (r)) ^ y0[q];                         \
  } }
#define TF_INJ_ALL(a, b)                                        \
  { _Pragma("unroll") for (int q = 0; q < 16; ++q) {            \
      y0[q] += (a); y1[q] += (b);                               \
  } }

// ---------- main -----------------------------------------------------------
__global__ __launch_bounds__(256, 6) void quantizer_channel_kernel(
    const float* __restrict__ x, const float* __restrict__ center,
    const float* __restrict__ ws, float* __restrict__ out, int n4)
{
  const int t = blockIdx.x * blockDim.x + threadIdx.x;
  if (t >= n4) return;

  const float4 xv = reinterpret_cast<const float4*>(x)[t];

  // ---- 16 interleaved threefry2x32 chains: counter = 16t + q, q = 4e+j
  uint32_t y0[16], y1[16];
  const uint32_t cb = (uint32_t)t * 16u + KS1;
#pragma unroll
  for (int q = 0; q < 16; ++q) { y0[q] = 0u; y1[q] = cb + (uint32_t)q; }
  TF_ROUND_ALL(13) TF_ROUND_ALL(15) TF_ROUND_ALL(26) TF_ROUND_ALL(6)
  TF_INJ_ALL(KS1, KS2 + 1u)
  TF_ROUND_ALL(17) TF_ROUND_ALL(29) TF_ROUND_ALL(16) TF_ROUND_ALL(24)
  TF_INJ_ALL(KS2, 0u + 2u)
  TF_ROUND_ALL(13) TF_ROUND_ALL(15) TF_ROUND_ALL(26) TF_ROUND_ALL(6)
  TF_INJ_ALL(0u, KS1 + 3u)
  TF_ROUND_ALL(17) TF_ROUND_ALL(29) TF_ROUND_ALL(16) TF_ROUND_ALL(24)
  TF_INJ_ALL(KS1, KS2 + 4u)
  TF_ROUND_ALL(13) TF_ROUND_ALL(15) TF_ROUND_ALL(26) TF_ROUND_ALL(6)
  TF_INJ_ALL(KS2, 0u + 5u)

  // ---- pack 4 flip masks, MSB-first: f = ((b0*2+b1)*2+b2)*2+b3
  uint32_t flip[4];
#pragma unroll
  for (int e = 0; e < 4; ++e) {
    uint32_t f = 0u;
#pragma unroll
    for (int j = 0; j < 4; ++j) {
      const uint32_t bits = y0[4 * e + j] ^ y1[4 * e + j];
      f = f + f + ((bits < BERN_LT) ? 1u : 0u);   // v_cmp + v_addc
    }
    flip[e] = f;
  }

  // ---- thresholds + luts (wave-uniform loads)
  const float4* wsf = (const float4*)ws;
  const float4 ta = wsf[0], tb = wsf[1], tc = wsf[2], td = wsf[3];
  const float T0 = ta.x, T1 = ta.y, T2  = ta.z, T3  = ta.w;
  const float T4 = tb.x, T5 = tb.y, T6  = tb.z, T7  = tb.w;
  const float T8 = tc.x, T9 = tc.y, T10 = tc.z, T11 = tc.w;
  const float T12 = td.x, T13 = td.y, T14 = td.z;
  const uint32_t lut0 = ((const uint32_t*)ws)[16];
  const uint32_t lut1 = ((const uint32_t*)ws)[17];

  const float xe[4] = {xv.x, xv.y, xv.z, xv.w};
  float oe[4];
#pragma unroll
  for (int e = 0; e < 4; ++e) {
    const float v = xe[e];
    // exact nearest-center via 4-level select tree over sorted cells
    const bool b3 = v > T7;
    const float s2 = b3 ? T11 : T3;
    const bool b2 = v > s2;
    const float s1 = b3 ? (b2 ? T13 : T9) : (b2 ? T5 : T1);
    const bool b1 = v > s1;
    const float u0 = b1 ? T2  : T0;
    const float u1 = b1 ? T6  : T4;
    const float u2 = b1 ? T10 : T8;
    const float u3 = b1 ? T14 : T12;
    const float s0 = b3 ? (b2 ? u3 : u2) : (b2 ? u1 : u0);
    const bool b0 = v > s0;
    const uint32_t shamt = (b2 ? 16u : 0u) | (b1 ? 8u : 0u) | (b0 ? 4u : 0u);
    const uint32_t word = b3 ? lut1 : lut0;
    const uint32_t best = (word >> shamt) & 15u;   // original center index

    oe[e] = center[best ^ flip[e]];                // 16 floats = 1 cache line
  }

  float4 o4;
  o4.x = oe[0]; o4.y = oe[1]; o4.z = oe[2]; o4.w = oe[3];
  reinterpret_cast<float4*>(out)[t] = o4;
}

extern "C" void kernel_launch(void* const* d_in, const int* in_sizes, int n_in,
                              void* d_out, int out_size, void* d_ws, size_t ws_size,
                              hipStream_t stream)
{
  const float* x      = (const float*)d_in[0];
  const float* center = (const float*)d_in[1];
  float* out          = (float*)d_out;
  float* ws           = (float*)d_ws;

  hipLaunchKernelGGL(quantizer_setup_kernel, dim3(1), dim3(64), 0, stream,
                     center, ws);

  const int N  = in_sizes[0];          // 32*256*32*32 = 8388608, divisible by 4
  const int n4 = N / 4;
  const int block = 256;
  const int grid  = (n4 + block - 1) / block;

  hipLaunchKernelGGL(quantizer_channel_kernel, dim3(grid), dim3(block), 0, stream,
                     x, center, ws, out, n4);
}